// Round 5
// baseline (101.100 us; speedup 1.0000x reference)
//
#include <hip/hip_runtime.h>
#include <hip/hip_cooperative_groups.h>
#include <math.h>

namespace cg = cooperative_groups;

constexpr int NG  = 8192;        // genes
constexpr int NM  = 256;         // sets
constexpr int NB  = 32;          // batch
constexpr int KR  = 128;         // k-span per mm tile
constexpr int NKB = NG / KR;     // 64
constexpr int MT  = 64;          // m-tile
constexpr int LMS = MT + 4;      // lm row stride (floats)
constexpr int LBS = NB + 2;      // lb row stride (float2)

// ws: cf float[NB][NG] (1MB) | part float[NKB][3][NB][NM] (6MB) | thr[NM] | sumN[NM]

__device__ __forceinline__ float sigmoidf(float x) {
  return __builtin_amdgcn_rcpf(1.0f + __builtin_amdgcn_exp2f(x * -1.442695041f));
}
__device__ __forceinline__ float qrtf(float x) {   // x^0.25
  return __builtin_amdgcn_sqrtf(__builtin_amdgcn_sqrtf(x));
}

__device__ __forceinline__ float block_sum(float v, float* red, int tid) {
  #pragma unroll
  for (int off = 32; off > 0; off >>= 1) v += __shfl_xor(v, off, 64);
  if ((tid & 63) == 0) red[tid >> 6] = v;
  __syncthreads();
  float r = red[0] + red[1] + red[2] + red[3];
  __syncthreads();
  return r;
}

__global__ __launch_bounds__(256) void k_fused(const float* __restrict__ R,
                                               const int* __restrict__ S,
                                               const float* __restrict__ W,
                                               float* __restrict__ cf,
                                               float* __restrict__ part,
                                               float* __restrict__ thr,
                                               float* __restrict__ sumN,
                                               float* __restrict__ out) {
  __shared__ float sh[KR * LMS + KR * LBS * 2];   // 69632 B
  float (*lm)[LMS]  = reinterpret_cast<float(*)[LMS]>(sh);
  float2 (*lb)[LBS] = reinterpret_cast<float2(*)[LBS]>(sh + KR * LMS);

  const int tid = threadIdx.x;
  const int bid = blockIdx.x;
  cg::grid_group grid = cg::this_grid();

  // ---------------- Phase 1: thr[m], sumN[m] (block m) + cf scatter (1/8 sample each)
  {
    const int m = bid;
    const float4* w4 = reinterpret_cast<const float4*>(W + (size_t)m * NG);
    float s = 0.f;
    #pragma unroll
    for (int i = tid; i < NG / 4; i += 256) {
      float4 v = w4[i];
      s += sigmoidf(v.x) + sigmoidf(v.y) + sigmoidf(v.z) + sigmoidf(v.w);
    }
    s = block_sum(s, sh, tid);
    const float tm = s * (0.3f / (float)NG);
    float sn = 0.f;
    #pragma unroll
    for (int i = tid; i < NG / 4; i += 256) {
      float4 v4 = w4[i];
      float vv[4] = {v4.x, v4.y, v4.z, v4.w};
      #pragma unroll
      for (int j = 0; j < 4; ++j) {
        float v = sigmoidf(vv[j]);
        v = (v < tm) ? v * 0.01f : v;
        sn += (v < 0.1f) ? 1.f : 0.f;
      }
    }
    sn = block_sum(sn, sh, tid);
    if (tid == 0) { thr[m] = tm; sumN[m] = sn; }

    // cf scatter: block handles sample b = bid&31, k-quarter q = bid>>5
    const int b = bid & 31, q = bid >> 5;
    const int4 g4 = reinterpret_cast<const int4*>(S + (size_t)b * NG)[q * 256 + tid];
    const int k = q * 1024 + tid * 4;
    float* cfb = cf + (size_t)b * NG;
    cfb[g4.x] = (float)(NG - k);
    cfb[g4.y] = (float)(NG - (k + 1));
    cfb[g4.z] = (float)(NG - (k + 2));
    cfb[g4.w] = (float)(NG - (k + 3));
  }

  grid.sync();

  // ---------------- Phase 2: one (kb, m-tile) per block; triple split-K matmul
  const int kb = bid & (NKB - 1);
  const int mt = bid >> 6;
  const int k0 = kb * KR;
  const int m0 = mt * MT;
  {
    {  // stage M: 64 rows x 128 k; thread (r, seg of 32 k)
      const int r   = tid & 63;
      const int seg = tid >> 6;
      const float tm = thr[m0 + r];
      const float4* src = reinterpret_cast<const float4*>(W + (size_t)(m0 + r) * NG + k0 + seg * 32);
      #pragma unroll
      for (int q = 0; q < 8; ++q) {
        float4 v4 = src[q];
        float vv[4] = {v4.x, v4.y, v4.z, v4.w};
        #pragma unroll
        for (int j = 0; j < 4; ++j) {
          float v = sigmoidf(vv[j]);
          v = (v < tm) ? v * 0.01f : v;        // _set_indicators where()
          const float ia = qrtf(v);            // ind^0.25
          lm[seg * 32 + q * 4 + j][r] = (v < 0.1f) ? -ia : ia;
        }
      }
    }
    {  // stage B: 32 b x 128 k; thread (b, kseg of 16); R^0.25 computed here
      const int b    = tid & 31;
      const int kseg = tid >> 5;
      const float4* rs = reinterpret_cast<const float4*>(R  + (size_t)b * NG + k0 + kseg * 16);
      const float4* cs = reinterpret_cast<const float4*>(cf + (size_t)b * NG + k0 + kseg * 16);
      #pragma unroll
      for (int q = 0; q < 4; ++q) {
        float4 rv = rs[q];
        float4 cv = cs[q];
        const int kk = kseg * 16 + q * 4;
        lb[kk + 0][b] = make_float2(qrtf(rv.x), cv.x);
        lb[kk + 1][b] = make_float2(qrtf(rv.y), cv.y);
        lb[kk + 2][b] = make_float2(qrtf(rv.z), cv.z);
        lb[kk + 3][b] = make_float2(qrtf(rv.w), cv.w);
      }
    }
    __syncthreads();

    const int mgrp = tid & 15;   // m = m0 + mgrp*4 + mi
    const int bgrp = tid >> 4;   // b = bgrp*2 + bi
    float aA[2][4] = {}, aB[2][4] = {}, aC[2][4] = {};

    #pragma unroll 8
    for (int kk = 0; kk < KR; ++kk) {
      const float4 mv = *reinterpret_cast<const float4*>(&lm[kk][mgrp * 4]);
      const float4 bv = *reinterpret_cast<const float4*>(&lb[kk][bgrp * 2]);
      const float mvv[4] = {mv.x, mv.y, mv.z, mv.w};
      const float ra[2]  = {bv.x, bv.z};
      const float cfv[2] = {bv.y, bv.w};
      #pragma unroll
      for (int mi = 0; mi < 4; ++mi) {
        const float ia = fabsf(mvv[mi]);
        const float nf = (mvv[mi] < 0.f) ? 1.f : 0.f;
        #pragma unroll
        for (int bi = 0; bi < 2; ++bi) {
          const float wq = ra[bi] * ia;
          aA[bi][mi] += wq;
          aB[bi][mi] = fmaf(wq, cfv[bi], aB[bi][mi]);
          aC[bi][mi] = fmaf(nf, cfv[bi], aC[bi][mi]);
        }
      }
    }

    #pragma unroll
    for (int bi = 0; bi < 2; ++bi) {
      const int b = bgrp * 2 + bi;
      #pragma unroll
      for (int mi = 0; mi < 4; ++mi) {
        const int m = m0 + mgrp * 4 + mi;
        part[((size_t)(kb * 3 + 0) * NB + b) * NM + m] = aA[bi][mi];
        part[((size_t)(kb * 3 + 1) * NB + b) * NM + m] = aB[bi][mi];
        part[((size_t)(kb * 3 + 2) * NB + b) * NM + m] = aC[bi][mi];
      }
    }
  }

  grid.sync();

  // ---------------- Phase 3: reduce over kb; block = (b, m-chunk of 32)
  {
    float* rA = sh;
    float* rB = sh + 256;
    float* rC = sh + 512;
    const int b  = bid >> 3;
    const int mc = bid & 7;
    const int ml = tid & 31;
    const int kg = tid >> 5;            // 0..7, each covers 8 kb
    const int m  = mc * 32 + ml;

    float sA = 0.f, sB = 0.f, sC = 0.f;
    #pragma unroll
    for (int t = 0; t < NKB / 8; ++t) {
      const int kk = kg * (NKB / 8) + t;
      const float* p = part + ((size_t)(kk * 3) * NB + b) * NM + m;
      sA += p[0];
      sB += p[(size_t)NB * NM];
      sC += p[2 * (size_t)NB * NM];
    }
    rA[tid] = sA; rB[tid] = sB; rC[tid] = sC;
    __syncthreads();
    #pragma unroll
    for (int off = 128; off >= 32; off >>= 1) {
      if (tid < off) { rA[tid] += rA[tid + off]; rB[tid] += rB[tid + off]; rC[tid] += rC[tid + off]; }
      __syncthreads();
    }
    if (tid < 32) {
      const float sN = sumN[m];
      out[(size_t)b * NM + m] =
          (rB[tid] / (rA[tid] + 1e-10f) - rC[tid] / (sN + 1e-10f)) * (1.0f / (float)NG);
    }
  }
}

extern "C" void kernel_launch(void* const* d_in, const int* in_sizes, int n_in,
                              void* d_out, int out_size, void* d_ws, size_t ws_size,
                              hipStream_t stream) {
  const float* R = (const float*)d_in[0];
  const int*   S = (const int*)d_in[1];
  const float* W = (const float*)d_in[2];
  float* out = (float*)d_out;

  char* ws = (char*)d_ws;
  float* cf   = (float*)ws;                          // 1 MB
  float* part = cf + (size_t)NB * NG;                // 6 MB
  float* thr  = part + (size_t)NKB * 3 * NB * NM;
  float* sumN = thr + NM;

  void* args[] = { (void*)&R, (void*)&S, (void*)&W, (void*)&cf,
                   (void*)&part, (void*)&thr, (void*)&sumN, (void*)&out };
  hipLaunchCooperativeKernel((const void*)k_fused, dim3(256), dim3(256), args, 0, stream);
}

// Round 6
// 32.316 us; speedup vs baseline: 3.1285x; 3.1285x over previous
//
#include <hip/hip_runtime.h>
#include <math.h>

constexpr int NG  = 8192;        // genes
constexpr int NM  = 256;         // sets
constexpr int NB  = 32;          // batch
constexpr int KR  = 64;          // k-span per k_mm block
constexpr int NKB = NG / KR;     // 128
constexpr int MT  = 32;          // m-tile per k_mm block
constexpr int LMK = KR + 2;      // lm row stride (floats)
constexpr int LBK = KR + 2;      // lb row stride (float2)

// ws: cf float[NB][NG] (1MB) | part float[NKB][3][NB][NM] (12MB) | thr[NM] | sumN[NM]

__device__ __forceinline__ float sigmoidf(float x) {
  return __builtin_amdgcn_rcpf(1.0f + __builtin_amdgcn_exp2f(x * -1.442695041f));
}
__device__ __forceinline__ float qrtf(float x) {   // x^0.25
  return __builtin_amdgcn_sqrtf(__builtin_amdgcn_sqrtf(x));
}

// blocks 0..NM-1: thr[m] + sumN[m] (sigmoids held in VGPRs, no LDS stash)
// blocks NM..NM+255: cf scatter; block handles sample b, eighth q (1024 elems)
__global__ __launch_bounds__(256) void k_prep(const int* __restrict__ S,
                                              const float* __restrict__ W,
                                              float* __restrict__ cf,
                                              float* __restrict__ thr,
                                              float* __restrict__ sumN) {
  __shared__ float red[4];
  const int tid = threadIdx.x;

  if (blockIdx.x < NM) {
    const int m = blockIdx.x;
    const float4* w4 = reinterpret_cast<const float4*>(W + (size_t)m * NG);
    float4 sg[8];
    float s = 0.f;
    #pragma unroll
    for (int q = 0; q < 8; ++q) {
      float4 v = w4[q * 256 + tid];          // coalesced
      sg[q] = make_float4(sigmoidf(v.x), sigmoidf(v.y), sigmoidf(v.z), sigmoidf(v.w));
      s += sg[q].x + sg[q].y + sg[q].z + sg[q].w;
    }
    #pragma unroll
    for (int off = 32; off > 0; off >>= 1) s += __shfl_xor(s, off, 64);
    if ((tid & 63) == 0) red[tid >> 6] = s;
    __syncthreads();
    const float tm = (red[0] + red[1] + red[2] + red[3]) * (0.3f / (float)NG);
    __syncthreads();
    float sn = 0.f;
    #pragma unroll
    for (int q = 0; q < 8; ++q) {
      float vv[4] = {sg[q].x, sg[q].y, sg[q].z, sg[q].w};
      #pragma unroll
      for (int j = 0; j < 4; ++j) {
        float v = vv[j];
        v = (v < tm) ? v * 0.01f : v;
        sn += (v < 0.1f) ? 1.f : 0.f;
      }
    }
    #pragma unroll
    for (int off = 32; off > 0; off >>= 1) sn += __shfl_xor(sn, off, 64);
    if ((tid & 63) == 0) red[tid >> 6] = sn;
    __syncthreads();
    if (tid == 0) { thr[m] = tm; sumN[m] = red[0] + red[1] + red[2] + red[3]; }
  } else {
    const int idx = blockIdx.x - NM;        // 0..255
    const int b = idx >> 3, q = idx & 7;    // sample, eighth
    const int4 g4 = reinterpret_cast<const int4*>(S + (size_t)b * NG)[q * 256 + tid];
    const int k = q * 1024 + tid * 4;
    float* cfb = cf + (size_t)b * NG;
    cfb[g4.x] = (float)(NG - k);
    cfb[g4.y] = (float)(NG - (k + 1));
    cfb[g4.z] = (float)(NG - (k + 2));
    cfb[g4.w] = (float)(NG - (k + 3));
  }
}

// Split-K triple matmul. grid (NKB, NM/MT) = (128, 8); 256 thr; 25 KB LDS.
// LDS row-major [m][k] / [b][k]; coalesced staging; compute eats 4 k per b128.
__global__ __launch_bounds__(256) void k_mm(const float* __restrict__ W,
                                            const float* __restrict__ thr,
                                            const float* __restrict__ R,
                                            const float* __restrict__ cf,
                                            float* __restrict__ part) {
  __shared__ float  lm[MT][LMK];    // +-ind^0.25
  __shared__ float2 lb[NB][LBK];    // (R^0.25, cf)
  const int tid = threadIdx.x;
  const int kb = blockIdx.x, k0 = kb * KR;
  const int m0 = blockIdx.y * MT;

  #pragma unroll
  for (int p = 0; p < 2; ++p) {     // stage M: 32 rows x 64 k
    const int idx = p * 256 + tid;
    const int r = idx >> 4, kq = idx & 15;
    const float tm = thr[m0 + r];
    float4 v4 = *reinterpret_cast<const float4*>(W + (size_t)(m0 + r) * NG + k0 + kq * 4);
    float vv[4] = {v4.x, v4.y, v4.z, v4.w};
    float oo[4];
    #pragma unroll
    for (int j = 0; j < 4; ++j) {
      float v = sigmoidf(vv[j]);
      v = (v < tm) ? v * 0.01f : v;          // _set_indicators where()
      const float ia = qrtf(v);
      oo[j] = (v < 0.1f) ? -ia : ia;         // sign bit = neg flag
    }
    *reinterpret_cast<float4*>(&lm[r][kq * 4]) = make_float4(oo[0], oo[1], oo[2], oo[3]);
  }
  #pragma unroll
  for (int p = 0; p < 2; ++p) {     // stage B: 32 rows x 64 k of (r^a, cf)
    const int idx = p * 256 + tid;
    const int b = idx >> 4, kq = idx & 15;
    float4 rv = *reinterpret_cast<const float4*>(R  + (size_t)b * NG + k0 + kq * 4);
    float4 cv = *reinterpret_cast<const float4*>(cf + (size_t)b * NG + k0 + kq * 4);
    float2* dst = &lb[b][kq * 4];
    dst[0] = make_float2(qrtf(rv.x), cv.x);
    dst[1] = make_float2(qrtf(rv.y), cv.y);
    dst[2] = make_float2(qrtf(rv.z), cv.z);
    dst[3] = make_float2(qrtf(rv.w), cv.w);
  }
  __syncthreads();

  const int mgrp = tid & 15;   // m = m0 + mgrp*2 + mi
  const int bgrp = tid >> 4;   // b = bgrp*2 + bi
  float aA[2][2] = {}, aB[2][2] = {}, aC[2][2] = {};

  #pragma unroll
  for (int kq = 0; kq < 16; ++kq) {
    const float4 am0 = *reinterpret_cast<const float4*>(&lm[mgrp * 2 + 0][kq * 4]);
    const float4 am1 = *reinterpret_cast<const float4*>(&lm[mgrp * 2 + 1][kq * 4]);
    const float4 b0l = *reinterpret_cast<const float4*>(&lb[bgrp * 2 + 0][kq * 4]);
    const float4 b0h = *reinterpret_cast<const float4*>(&lb[bgrp * 2 + 0][kq * 4 + 2]);
    const float4 b1l = *reinterpret_cast<const float4*>(&lb[bgrp * 2 + 1][kq * 4]);
    const float4 b1h = *reinterpret_cast<const float4*>(&lb[bgrp * 2 + 1][kq * 4 + 2]);
    const float am0a[4] = {am0.x, am0.y, am0.z, am0.w};
    const float am1a[4] = {am1.x, am1.y, am1.z, am1.w};
    const float ra0[4]  = {b0l.x, b0l.z, b0h.x, b0h.z};
    const float cf0[4]  = {b0l.y, b0l.w, b0h.y, b0h.w};
    const float ra1[4]  = {b1l.x, b1l.z, b1h.x, b1h.z};
    const float cf1[4]  = {b1l.y, b1l.w, b1h.y, b1h.w};
    #pragma unroll
    for (int j = 0; j < 4; ++j) {
      const float ia[2] = {fabsf(am0a[j]), fabsf(am1a[j])};
      const float nf[2] = {(am0a[j] < 0.f) ? 1.f : 0.f, (am1a[j] < 0.f) ? 1.f : 0.f};
      const float ra[2] = {ra0[j], ra1[j]};
      const float cw[2] = {cf0[j], cf1[j]};
      #pragma unroll
      for (int mi = 0; mi < 2; ++mi) {
        #pragma unroll
        for (int bi = 0; bi < 2; ++bi) {
          const float wq = ra[bi] * ia[mi];
          aA[bi][mi] += wq;
          aB[bi][mi] = fmaf(wq, cw[bi], aB[bi][mi]);
          aC[bi][mi] = fmaf(nf[mi], cw[bi], aC[bi][mi]);
        }
      }
    }
  }

  #pragma unroll
  for (int bi = 0; bi < 2; ++bi) {
    const int b = bgrp * 2 + bi;
    #pragma unroll
    for (int mi = 0; mi < 2; ++mi) {
      const int m = m0 + mgrp * 2 + mi;
      part[((size_t)(kb * 3 + 0) * NB + b) * NM + m] = aA[bi][mi];
      part[((size_t)(kb * 3 + 1) * NB + b) * NM + m] = aB[bi][mi];
      part[((size_t)(kb * 3 + 2) * NB + b) * NM + m] = aC[bi][mi];
    }
  }
}

// grid 256: block = (b, m-chunk of 32); tid = kg(8) x ml(32); LDS tree over kg.
__global__ __launch_bounds__(256) void k_final(const float* __restrict__ part,
                                               const float* __restrict__ sumN,
                                               float* __restrict__ out) {
  __shared__ float rA[256], rB[256], rC[256];
  const int tid = threadIdx.x;
  const int b   = blockIdx.x >> 3;
  const int mc  = blockIdx.x & 7;
  const int ml  = tid & 31;
  const int kg  = tid >> 5;             // 0..7, each covers 16 kb
  const int m   = mc * 32 + ml;

  float sA = 0.f, sB = 0.f, sC = 0.f;
  #pragma unroll 4
  for (int t = 0; t < NKB / 8; ++t) {
    const int kb = kg * (NKB / 8) + t;
    const float* p = part + ((size_t)(kb * 3) * NB + b) * NM + m;
    sA += p[0];
    sB += p[(size_t)NB * NM];
    sC += p[2 * (size_t)NB * NM];
  }
  rA[tid] = sA; rB[tid] = sB; rC[tid] = sC;
  __syncthreads();
  #pragma unroll
  for (int off = 128; off >= 32; off >>= 1) {
    if (tid < off) { rA[tid] += rA[tid + off]; rB[tid] += rB[tid + off]; rC[tid] += rC[tid + off]; }
    __syncthreads();
  }
  if (tid < 32) {
    const float sN = sumN[m];
    out[(size_t)b * NM + m] = (rB[tid] / (rA[tid] + 1e-10f) - rC[tid] / (sN + 1e-10f)) * (1.0f / (float)NG);
  }
}

extern "C" void kernel_launch(void* const* d_in, const int* in_sizes, int n_in,
                              void* d_out, int out_size, void* d_ws, size_t ws_size,
                              hipStream_t stream) {
  const float* R = (const float*)d_in[0];
  const int*   S = (const int*)d_in[1];
  const float* W = (const float*)d_in[2];
  float* out = (float*)d_out;

  char* ws = (char*)d_ws;
  float* cf   = (float*)ws;                          // 1 MB
  float* part = cf + (size_t)NB * NG;                // 12 MB
  float* thr  = part + (size_t)NKB * 3 * NB * NM;
  float* sumN = thr + NM;

  k_prep <<<dim3(NM + 256), dim3(256), 0, stream>>>(S, W, cf, thr, sumN);
  k_mm   <<<dim3(NKB, NM / MT), dim3(256), 0, stream>>>(W, thr, R, cf, part);
  k_final<<<dim3(NB * 8), dim3(256), 0, stream>>>(part, sumN, out);
}

// Round 7
// 27.534 us; speedup vs baseline: 3.6718x; 1.1737x over previous
//
#include <hip/hip_runtime.h>
#include <math.h>

constexpr int NG  = 8192;        // genes
constexpr int NM  = 256;         // sets
constexpr int NB  = 32;          // batch
constexpr int KR  = 64;          // k-span per k_mm block
constexpr int NKB = NG / KR;     // 128

// ws: cf float[NB][NG] (1MB) | part float[NKB][3][NM][NB] (12.6MB) | thr[NM] | sumN[NM]

using bf16x8 = __attribute__((ext_vector_type(8))) short;
using f32x4  = __attribute__((ext_vector_type(4))) float;

__device__ __forceinline__ float sigmoidf(float x) {
  return __builtin_amdgcn_rcpf(1.0f + __builtin_amdgcn_exp2f(x * -1.442695041f));
}
__device__ __forceinline__ float qrtf(float x) {   // x^0.25
  return __builtin_amdgcn_sqrtf(__builtin_amdgcn_sqrtf(x));
}
__device__ __forceinline__ short bfr(float f) {    // fp32 -> bf16 (RNE)
  unsigned x = __float_as_uint(f);
  return (short)((x + 0x7fffu + ((x >> 16) & 1u)) >> 16);
}

// blocks 0..NM-1: thr[m] + sumN[m] (sigmoids held in VGPRs)
// blocks NM..NM+255: cf scatter; block handles sample b, eighth q
__global__ __launch_bounds__(256) void k_prep(const int* __restrict__ S,
                                              const float* __restrict__ W,
                                              float* __restrict__ cf,
                                              float* __restrict__ thr,
                                              float* __restrict__ sumN) {
  __shared__ float red[4];
  const int tid = threadIdx.x;

  if (blockIdx.x < NM) {
    const int m = blockIdx.x;
    const float4* w4 = reinterpret_cast<const float4*>(W + (size_t)m * NG);
    float4 sg[8];
    float s = 0.f;
    #pragma unroll
    for (int q = 0; q < 8; ++q) {
      float4 v = w4[q * 256 + tid];          // coalesced
      sg[q] = make_float4(sigmoidf(v.x), sigmoidf(v.y), sigmoidf(v.z), sigmoidf(v.w));
      s += sg[q].x + sg[q].y + sg[q].z + sg[q].w;
    }
    #pragma unroll
    for (int off = 32; off > 0; off >>= 1) s += __shfl_xor(s, off, 64);
    if ((tid & 63) == 0) red[tid >> 6] = s;
    __syncthreads();
    const float tm = (red[0] + red[1] + red[2] + red[3]) * (0.3f / (float)NG);
    __syncthreads();
    float sn = 0.f;
    #pragma unroll
    for (int q = 0; q < 8; ++q) {
      float vv[4] = {sg[q].x, sg[q].y, sg[q].z, sg[q].w};
      #pragma unroll
      for (int j = 0; j < 4; ++j) {
        float v = vv[j];
        v = (v < tm) ? v * 0.01f : v;
        sn += (v < 0.1f) ? 1.f : 0.f;
      }
    }
    #pragma unroll
    for (int off = 32; off > 0; off >>= 1) sn += __shfl_xor(sn, off, 64);
    if ((tid & 63) == 0) red[tid >> 6] = sn;
    __syncthreads();
    if (tid == 0) { thr[m] = tm; sumN[m] = red[0] + red[1] + red[2] + red[3]; }
  } else {
    const int idx = blockIdx.x - NM;        // 0..255
    const int b = idx >> 3, q = idx & 7;
    const int4 g4 = reinterpret_cast<const int4*>(S + (size_t)b * NG)[q * 256 + tid];
    const int k = q * 1024 + tid * 4;
    float* cfb = cf + (size_t)b * NG;
    cfb[g4.x] = (float)(NG - k);
    cfb[g4.y] = (float)(NG - (k + 1));
    cfb[g4.z] = (float)(NG - (k + 2));
    cfb[g4.w] = (float)(NG - (k + 3));
  }
}

// MFMA split-K: grid (NKB, NM/32); 4 waves/block, each owns a 16m x 16b tile.
// No LDS, no barriers: fragments built in-lane from global loads.
// Operand layout (gfx950 mfma_f32_16x16x32_bf16): lane supplies its
// row/col = lane&15 at k = 8*(lane>>4)+e; D: m = 4*(lane>>4)+reg, b = lane&15.
__global__ __launch_bounds__(256) void k_mm(const float* __restrict__ W,
                                            const float* __restrict__ thr,
                                            const float* __restrict__ R,
                                            const float* __restrict__ cf,
                                            float* __restrict__ part) {
  const int tid  = threadIdx.x;
  const int kb   = blockIdx.x;          // k-block
  const int mt   = blockIdx.y;          // m-tile of 32
  const int wv   = tid >> 6;
  const int mw   = wv >> 1, bw = wv & 1;
  const int lane = tid & 63;
  const int lr   = lane & 15, lk = lane >> 4;

  const int m = mt * 32 + mw * 16 + lr;   // A-side row this lane supplies
  const int b = bw * 16 + lr;             // B-side col this lane supplies
  const float tm = thr[m];

  f32x4 accA = {0.f, 0.f, 0.f, 0.f};
  f32x4 accB = {0.f, 0.f, 0.f, 0.f};
  f32x4 accC = {0.f, 0.f, 0.f, 0.f};

  #pragma unroll
  for (int c = 0; c < KR / 32; ++c) {
    const int g = kb * KR + c * 32 + lk * 8;

    // ---- A-side fragments: ia = ind^0.25 (bf16), nf = (ind<0.1) (bf16 1/0)
    const float4 w0 = *reinterpret_cast<const float4*>(W + (size_t)m * NG + g);
    const float4 w1 = *reinterpret_cast<const float4*>(W + (size_t)m * NG + g + 4);
    const float wa[8] = {w0.x, w0.y, w0.z, w0.w, w1.x, w1.y, w1.z, w1.w};
    bf16x8 fia, fnf;
    #pragma unroll
    for (int e = 0; e < 8; ++e) {
      float v = sigmoidf(wa[e]);
      v = (v < tm) ? v * 0.01f : v;            // _set_indicators where()
      fia[e] = bfr(qrtf(v));
      fnf[e] = (v < 0.1f) ? (short)0x3F80 : (short)0;
    }

    // ---- B-side fragments: ra = R^0.25, rc = ra*cf, cf
    const float4 r0 = *reinterpret_cast<const float4*>(R  + (size_t)b * NG + g);
    const float4 r1 = *reinterpret_cast<const float4*>(R  + (size_t)b * NG + g + 4);
    const float4 c0 = *reinterpret_cast<const float4*>(cf + (size_t)b * NG + g);
    const float4 c1 = *reinterpret_cast<const float4*>(cf + (size_t)b * NG + g + 4);
    const float rr[8] = {r0.x, r0.y, r0.z, r0.w, r1.x, r1.y, r1.z, r1.w};
    const float cc[8] = {c0.x, c0.y, c0.z, c0.w, c1.x, c1.y, c1.z, c1.w};
    bf16x8 fra, frc, fcf;
    #pragma unroll
    for (int e = 0; e < 8; ++e) {
      const float ra = qrtf(rr[e]);
      fra[e] = bfr(ra);
      frc[e] = bfr(ra * cc[e]);
      fcf[e] = bfr(cc[e]);
    }

    accA = __builtin_amdgcn_mfma_f32_16x16x32_bf16(fia, fra, accA, 0, 0, 0);
    accB = __builtin_amdgcn_mfma_f32_16x16x32_bf16(fia, frc, accB, 0, 0, 0);
    accC = __builtin_amdgcn_mfma_f32_16x16x32_bf16(fnf, fcf, accC, 0, 0, 0);
  }

  // store: lane, reg i -> (m = mt*32 + mw*16 + 4*lk + i, b = bw*16 + lr)
  const int md = mt * 32 + mw * 16 + 4 * lk;
  const int bd = bw * 16 + lr;
  #pragma unroll
  for (int i = 0; i < 4; ++i) {
    part[((size_t)(kb * 3 + 0) * NM + md + i) * NB + bd] = accA[i];
    part[((size_t)(kb * 3 + 1) * NM + md + i) * NB + bd] = accB[i];
    part[((size_t)(kb * 3 + 2) * NM + md + i) * NB + bd] = accC[i];
  }
}

// grid NM: block m; tid = (kg 8 x b 32); coalesced part reads, LDS tree over kg.
__global__ __launch_bounds__(256) void k_final(const float* __restrict__ part,
                                               const float* __restrict__ sumN,
                                               float* __restrict__ out) {
  __shared__ float rA[256], rB[256], rC[256];
  const int tid = threadIdx.x;
  const int m   = blockIdx.x;
  const int b   = tid & 31;
  const int kg  = tid >> 5;             // 0..7, each covers 16 kb

  float sA = 0.f, sB = 0.f, sC = 0.f;
  #pragma unroll 4
  for (int t = 0; t < NKB / 8; ++t) {
    const int kb = kg * (NKB / 8) + t;
    const float* p = part + ((size_t)(kb * 3) * NM + m) * NB + b;
    sA += p[0];
    sB += p[(size_t)NM * NB];
    sC += p[2 * (size_t)NM * NB];
  }
  rA[tid] = sA; rB[tid] = sB; rC[tid] = sC;
  __syncthreads();
  if (tid < 128) { rA[tid] += rA[tid + 128]; rB[tid] += rB[tid + 128]; rC[tid] += rC[tid + 128]; }
  __syncthreads();
  if (tid < 64)  { rA[tid] += rA[tid + 64];  rB[tid] += rB[tid + 64];  rC[tid] += rC[tid + 64]; }
  __syncthreads();
  if (tid < 32) {
    const float a = rA[tid] + rA[tid + 32];
    const float bb = rB[tid] + rB[tid + 32];
    const float c = rC[tid] + rC[tid + 32];
    const float sN = sumN[m];
    out[(size_t)tid * NM + m] = (bb / (a + 1e-10f) - c / (sN + 1e-10f)) * (1.0f / (float)NG);
  }
}

extern "C" void kernel_launch(void* const* d_in, const int* in_sizes, int n_in,
                              void* d_out, int out_size, void* d_ws, size_t ws_size,
                              hipStream_t stream) {
  const float* R = (const float*)d_in[0];
  const int*   S = (const int*)d_in[1];
  const float* W = (const float*)d_in[2];
  float* out = (float*)d_out;

  char* ws = (char*)d_ws;
  float* cf   = (float*)ws;                          // 1 MB
  float* part = cf + (size_t)NB * NG;                // 12.6 MB
  float* thr  = part + (size_t)NKB * 3 * NM * NB;
  float* sumN = thr + NM;

  k_prep <<<dim3(NM + 256), dim3(256), 0, stream>>>(S, W, cf, thr, sumN);
  k_mm   <<<dim3(NKB, NM / 32), dim3(256), 0, stream>>>(W, thr, R, cf, part);
  k_final<<<dim3(NM), dim3(256), 0, stream>>>(part, sumN, out);
}

// Round 8
// 22.359 us; speedup vs baseline: 4.5217x; 1.2315x over previous
//
#include <hip/hip_runtime.h>
#include <math.h>

constexpr int NG  = 8192;        // genes
constexpr int NM  = 256;         // sets
constexpr int NB  = 32;          // batch
constexpr int KR  = 128;         // k-span per k_mm block
constexpr int NKB = NG / KR;     // 64

// ws: cf float[NB][NG] (1MB) | part float[NKB][3][NM][NB] (6.3MB) | thr[NM] | sumN[NM]

using bf16x8 = __attribute__((ext_vector_type(8))) short;
using f32x4  = __attribute__((ext_vector_type(4))) float;

__device__ __forceinline__ float sigmoidf(float x) {
  return __builtin_amdgcn_rcpf(1.0f + __builtin_amdgcn_exp2f(x * -1.442695041f));
}
__device__ __forceinline__ float qrtf(float x) {   // x^0.25
  return __builtin_amdgcn_sqrtf(__builtin_amdgcn_sqrtf(x));
}
__device__ __forceinline__ short bfr(float f) {    // fp32 -> bf16 (RNE)
  unsigned x = __float_as_uint(f);
  return (short)((x + 0x7fffu + ((x >> 16) & 1u)) >> 16);
}

// blocks 0..NM-1: thr[m] + sumN[m] (sigmoids held in VGPRs)
// blocks NM..NM+NB-1: cf row built in LDS (fast random writes), then
// streamed out coalesced — no global RMW scatter.
__global__ __launch_bounds__(256) void k_prep(const int* __restrict__ S,
                                              const float* __restrict__ W,
                                              float* __restrict__ cf,
                                              float* __restrict__ thr,
                                              float* __restrict__ sumN) {
  const int tid = threadIdx.x;

  if (blockIdx.x < NM) {
    __shared__ float red[4];
    const int m = blockIdx.x;
    const float4* w4 = reinterpret_cast<const float4*>(W + (size_t)m * NG);
    float4 sg[8];
    float s = 0.f;
    #pragma unroll
    for (int q = 0; q < 8; ++q) {
      float4 v = w4[q * 256 + tid];          // coalesced
      sg[q] = make_float4(sigmoidf(v.x), sigmoidf(v.y), sigmoidf(v.z), sigmoidf(v.w));
      s += sg[q].x + sg[q].y + sg[q].z + sg[q].w;
    }
    #pragma unroll
    for (int off = 32; off > 0; off >>= 1) s += __shfl_xor(s, off, 64);
    if ((tid & 63) == 0) red[tid >> 6] = s;
    __syncthreads();
    const float tm = (red[0] + red[1] + red[2] + red[3]) * (0.3f / (float)NG);
    __syncthreads();
    float sn = 0.f;
    #pragma unroll
    for (int q = 0; q < 8; ++q) {
      float vv[4] = {sg[q].x, sg[q].y, sg[q].z, sg[q].w};
      #pragma unroll
      for (int j = 0; j < 4; ++j) {
        float v = vv[j];
        v = (v < tm) ? v * 0.01f : v;
        sn += (v < 0.1f) ? 1.f : 0.f;
      }
    }
    #pragma unroll
    for (int off = 32; off > 0; off >>= 1) sn += __shfl_xor(sn, off, 64);
    if ((tid & 63) == 0) red[tid >> 6] = sn;
    __syncthreads();
    if (tid == 0) { thr[m] = tm; sumN[m] = red[0] + red[1] + red[2] + red[3]; }
  } else {
    __shared__ float row[NG];               // 32 KB cf row
    const int b = blockIdx.x - NM;
    const int4* s4 = reinterpret_cast<const int4*>(S + (size_t)b * NG);
    #pragma unroll
    for (int q = 0; q < 8; ++q) {
      const int i = q * 256 + tid;
      const int4 g4 = s4[i];                // coalesced read
      const int k = i * 4;
      row[g4.x] = (float)(NG - k);          // LDS scatter (cheap)
      row[g4.y] = (float)(NG - (k + 1));
      row[g4.z] = (float)(NG - (k + 2));
      row[g4.w] = (float)(NG - (k + 3));
    }
    __syncthreads();
    float4* dst = reinterpret_cast<float4*>(cf + (size_t)b * NG);
    const float4* src = reinterpret_cast<const float4*>(row);
    #pragma unroll
    for (int q = 0; q < 8; ++q)
      dst[q * 256 + tid] = src[q * 256 + tid];   // coalesced write
  }
}

// MFMA split-K: grid (NKB, NM/32); 4 waves/block, each owns a 16m x 16b tile.
// No LDS, no barriers: fragments built in-lane from global loads.
// Operand layout (gfx950 mfma_f32_16x16x32_bf16): lane supplies its
// row/col = lane&15 at k = 8*(lane>>4)+e; D: m = 4*(lane>>4)+reg, b = lane&15.
__global__ __launch_bounds__(256) void k_mm(const float* __restrict__ W,
                                            const float* __restrict__ thr,
                                            const float* __restrict__ R,
                                            const float* __restrict__ cf,
                                            float* __restrict__ part) {
  const int tid  = threadIdx.x;
  const int kb   = blockIdx.x;          // k-block
  const int mt   = blockIdx.y;          // m-tile of 32
  const int wv   = tid >> 6;
  const int mw   = wv >> 1, bw = wv & 1;
  const int lane = tid & 63;
  const int lr   = lane & 15, lk = lane >> 4;

  const int m = mt * 32 + mw * 16 + lr;   // A-side row this lane supplies
  const int b = bw * 16 + lr;             // B-side col this lane supplies
  const float tm = thr[m];

  f32x4 accA = {0.f, 0.f, 0.f, 0.f};
  f32x4 accB = {0.f, 0.f, 0.f, 0.f};
  f32x4 accC = {0.f, 0.f, 0.f, 0.f};

  #pragma unroll
  for (int c = 0; c < KR / 32; ++c) {
    const int g = kb * KR + c * 32 + lk * 8;

    // ---- A-side fragments: ia = ind^0.25 (bf16), nf = (ind<0.1) (bf16 1/0)
    const float4 w0 = *reinterpret_cast<const float4*>(W + (size_t)m * NG + g);
    const float4 w1 = *reinterpret_cast<const float4*>(W + (size_t)m * NG + g + 4);
    const float wa[8] = {w0.x, w0.y, w0.z, w0.w, w1.x, w1.y, w1.z, w1.w};
    bf16x8 fia, fnf;
    #pragma unroll
    for (int e = 0; e < 8; ++e) {
      float v = sigmoidf(wa[e]);
      v = (v < tm) ? v * 0.01f : v;            // _set_indicators where()
      fia[e] = bfr(qrtf(v));
      fnf[e] = (v < 0.1f) ? (short)0x3F80 : (short)0;
    }

    // ---- B-side fragments: ra = R^0.25, rc = ra*cf, cf
    const float4 r0 = *reinterpret_cast<const float4*>(R  + (size_t)b * NG + g);
    const float4 r1 = *reinterpret_cast<const float4*>(R  + (size_t)b * NG + g + 4);
    const float4 c0 = *reinterpret_cast<const float4*>(cf + (size_t)b * NG + g);
    const float4 c1 = *reinterpret_cast<const float4*>(cf + (size_t)b * NG + g + 4);
    const float rr[8] = {r0.x, r0.y, r0.z, r0.w, r1.x, r1.y, r1.z, r1.w};
    const float cc[8] = {c0.x, c0.y, c0.z, c0.w, c1.x, c1.y, c1.z, c1.w};
    bf16x8 fra, frc, fcf;
    #pragma unroll
    for (int e = 0; e < 8; ++e) {
      const float ra = qrtf(rr[e]);
      fra[e] = bfr(ra);
      frc[e] = bfr(ra * cc[e]);
      fcf[e] = bfr(cc[e]);
    }

    accA = __builtin_amdgcn_mfma_f32_16x16x32_bf16(fia, fra, accA, 0, 0, 0);
    accB = __builtin_amdgcn_mfma_f32_16x16x32_bf16(fia, frc, accB, 0, 0, 0);
    accC = __builtin_amdgcn_mfma_f32_16x16x32_bf16(fnf, fcf, accC, 0, 0, 0);
  }

  // store: lane, reg i -> (m = mt*32 + mw*16 + 4*lk + i, b = bw*16 + lr)
  const int md = mt * 32 + mw * 16 + 4 * lk;
  const int bd = bw * 16 + lr;
  #pragma unroll
  for (int i = 0; i < 4; ++i) {
    part[((size_t)(kb * 3 + 0) * NM + md + i) * NB + bd] = accA[i];
    part[((size_t)(kb * 3 + 1) * NM + md + i) * NB + bd] = accB[i];
    part[((size_t)(kb * 3 + 2) * NM + md + i) * NB + bd] = accC[i];
  }
}

// grid NM: block m; tid = (kg 8 x b 32); coalesced part reads, LDS tree over kg.
__global__ __launch_bounds__(256) void k_final(const float* __restrict__ part,
                                               const float* __restrict__ sumN,
                                               float* __restrict__ out) {
  __shared__ float rA[256], rB[256], rC[256];
  const int tid = threadIdx.x;
  const int m   = blockIdx.x;
  const int b   = tid & 31;
  const int kg  = tid >> 5;             // 0..7, each covers 8 kb

  float sA = 0.f, sB = 0.f, sC = 0.f;
  #pragma unroll
  for (int t = 0; t < NKB / 8; ++t) {
    const int kb = kg * (NKB / 8) + t;
    const float* p = part + ((size_t)(kb * 3) * NM + m) * NB + b;
    sA += p[0];
    sB += p[(size_t)NM * NB];
    sC += p[2 * (size_t)NM * NB];
  }
  rA[tid] = sA; rB[tid] = sB; rC[tid] = sC;
  __syncthreads();
  if (tid < 128) { rA[tid] += rA[tid + 128]; rB[tid] += rB[tid + 128]; rC[tid] += rC[tid + 128]; }
  __syncthreads();
  if (tid < 64)  { rA[tid] += rA[tid + 64];  rB[tid] += rB[tid + 64];  rC[tid] += rC[tid + 64]; }
  __syncthreads();
  if (tid < 32) {
    const float a  = rA[tid] + rA[tid + 32];
    const float bb = rB[tid] + rB[tid + 32];
    const float c  = rC[tid] + rC[tid + 32];
    const float sN = sumN[m];
    out[(size_t)tid * NM + m] = (bb / (a + 1e-10f) - c / (sN + 1e-10f)) * (1.0f / (float)NG);
  }
}

extern "C" void kernel_launch(void* const* d_in, const int* in_sizes, int n_in,
                              void* d_out, int out_size, void* d_ws, size_t ws_size,
                              hipStream_t stream) {
  const float* R = (const float*)d_in[0];
  const int*   S = (const int*)d_in[1];
  const float* W = (const float*)d_in[2];
  float* out = (float*)d_out;

  char* ws = (char*)d_ws;
  float* cf   = (float*)ws;                          // 1 MB
  float* part = cf + (size_t)NB * NG;                // 6.3 MB
  float* thr  = part + (size_t)NKB * 3 * NM * NB;
  float* sumN = thr + NM;

  k_prep <<<dim3(NM + NB), dim3(256), 0, stream>>>(S, W, cf, thr, sumN);
  k_mm   <<<dim3(NKB, NM / 32), dim3(256), 0, stream>>>(W, thr, R, cf, part);
  k_final<<<dim3(NM), dim3(256), 0, stream>>>(part, sumN, out);
}

// Round 9
// 20.412 us; speedup vs baseline: 4.9530x; 1.0954x over previous
//
#include <hip/hip_runtime.h>
#include <math.h>

constexpr int NG  = 8192;        // genes
constexpr int NM  = 256;         // sets
constexpr int NB  = 32;          // batch
constexpr int KR  = 256;         // k-span per k_mm block
constexpr int NKB = NG / KR;     // 32

// ws: pA bf16[NM][NG] (4MB, sign=neg) | pB bf16[3][NB][NG] (1.5MB: ra, ra*cf, cf)
//     | part f32[NKB][3][NM][NB] (3.2MB) | sumN f32[NM]

using bf16x8 = __attribute__((ext_vector_type(8))) short;
using s16x4  = __attribute__((ext_vector_type(4))) short;
using f32x4  = __attribute__((ext_vector_type(4))) float;

__device__ __forceinline__ float sigmoidf(float x) {
  return __builtin_amdgcn_rcpf(1.0f + __builtin_amdgcn_exp2f(x * -1.442695041f));
}
__device__ __forceinline__ float qrtf(float x) {   // x^0.25
  return __builtin_amdgcn_sqrtf(__builtin_amdgcn_sqrtf(x));
}
__device__ __forceinline__ short bfr(float f) {    // fp32 -> bf16 (RNE)
  unsigned x = __float_as_uint(f);
  return (short)((x + 0x7fffu + ((x >> 16) & 1u)) >> 16);
}

// blocks 0..NM-1: thr/sumN + write pA[m][:] = +-ind^0.25 bf16 (sign = neg)
// blocks NM..NM+NB-1: cf row in LDS, then write pB planes (ra, ra*cf, cf) bf16
__global__ __launch_bounds__(256) void k_prep(const int* __restrict__ S,
                                              const float* __restrict__ W,
                                              const float* __restrict__ R,
                                              unsigned short* __restrict__ pA,
                                              unsigned short* __restrict__ pB,
                                              float* __restrict__ sumN) {
  const int tid = threadIdx.x;

  if (blockIdx.x < NM) {
    __shared__ float red[4];
    const int m = blockIdx.x;
    const float4* w4 = reinterpret_cast<const float4*>(W + (size_t)m * NG);
    float4 sg[8];
    float s = 0.f;
    #pragma unroll
    for (int q = 0; q < 8; ++q) {
      float4 v = w4[q * 256 + tid];          // coalesced
      sg[q] = make_float4(sigmoidf(v.x), sigmoidf(v.y), sigmoidf(v.z), sigmoidf(v.w));
      s += sg[q].x + sg[q].y + sg[q].z + sg[q].w;
    }
    #pragma unroll
    for (int off = 32; off > 0; off >>= 1) s += __shfl_xor(s, off, 64);
    if ((tid & 63) == 0) red[tid >> 6] = s;
    __syncthreads();
    const float tm = (red[0] + red[1] + red[2] + red[3]) * (0.3f / (float)NG);
    float sn = 0.f;
    s16x4* dst = reinterpret_cast<s16x4*>(pA + (size_t)m * NG);
    #pragma unroll
    for (int q = 0; q < 8; ++q) {
      float vv[4] = {sg[q].x, sg[q].y, sg[q].z, sg[q].w};
      s16x4 po;
      #pragma unroll
      for (int j = 0; j < 4; ++j) {
        float v = vv[j];
        v = (v < tm) ? v * 0.01f : v;          // _set_indicators where()
        const bool ng = v < 0.1f;
        po[j] = (short)(bfr(qrtf(v)) | (ng ? (short)0x8000 : (short)0));
        sn += ng ? 1.f : 0.f;
      }
      dst[q * 256 + tid] = po;                 // coalesced 8B stores
    }
    #pragma unroll
    for (int off = 32; off > 0; off >>= 1) sn += __shfl_xor(sn, off, 64);
    if ((tid & 63) == 0) red[tid >> 6] = sn;
    __syncthreads();
    if (tid == 0) sumN[m] = red[0] + red[1] + red[2] + red[3];
  } else {
    __shared__ float row[NG];               // 32 KB cf row
    const int b = blockIdx.x - NM;
    const int4* s4 = reinterpret_cast<const int4*>(S + (size_t)b * NG);
    #pragma unroll
    for (int q = 0; q < 8; ++q) {
      const int i = q * 256 + tid;
      const int4 g4 = s4[i];                // coalesced read
      const int k = i * 4;
      row[g4.x] = (float)(NG - k);          // LDS scatter (cheap)
      row[g4.y] = (float)(NG - (k + 1));
      row[g4.z] = (float)(NG - (k + 2));
      row[g4.w] = (float)(NG - (k + 3));
    }
    __syncthreads();
    const float4* r4 = reinterpret_cast<const float4*>(R + (size_t)b * NG);
    const float4* c4 = reinterpret_cast<const float4*>(row);
    s16x4* dra = reinterpret_cast<s16x4*>(pB + 0 * (size_t)NB * NG + (size_t)b * NG);
    s16x4* drc = reinterpret_cast<s16x4*>(pB + 1 * (size_t)NB * NG + (size_t)b * NG);
    s16x4* dcf = reinterpret_cast<s16x4*>(pB + 2 * (size_t)NB * NG + (size_t)b * NG);
    #pragma unroll
    for (int q = 0; q < 8; ++q) {
      const float4 r = r4[q * 256 + tid];
      const float4 c = c4[q * 256 + tid];
      const float ra[4] = {qrtf(r.x), qrtf(r.y), qrtf(r.z), qrtf(r.w)};
      const float cc[4] = {c.x, c.y, c.z, c.w};
      s16x4 pra, prc, pcf;
      #pragma unroll
      for (int j = 0; j < 4; ++j) {
        pra[j] = bfr(ra[j]);
        prc[j] = bfr(ra[j] * cc[j]);           // product at fp32, then round
        pcf[j] = bfr(cc[j]);
      }
      dra[q * 256 + tid] = pra;
      drc[q * 256 + tid] = prc;
      dcf[q * 256 + tid] = pcf;
    }
  }
}

// MFMA split-K: grid (NKB, NM/32); 4 waves/block, each owns a 16m x 16b tile.
// Pure load+MFMA: all operands prepacked bf16. No LDS, no barriers.
// Layout (m89-verified): lane supplies row/col = lane&15 at k = 8*(lane>>4)+e;
// D: m = 4*(lane>>4)+reg, b = lane&15.
__global__ __launch_bounds__(256) void k_mm(const unsigned short* __restrict__ pA,
                                            const unsigned short* __restrict__ pB,
                                            float* __restrict__ part) {
  const int tid  = threadIdx.x;
  const int kb   = blockIdx.x;          // k-block
  const int mt   = blockIdx.y;          // m-tile of 32
  const int wv   = tid >> 6;
  const int mw   = wv >> 1, bw = wv & 1;
  const int lane = tid & 63;
  const int lr   = lane & 15, lk = lane >> 4;

  const int m = mt * 32 + mw * 16 + lr;   // A-side row this lane supplies
  const int b = bw * 16 + lr;             // B-side col this lane supplies

  const unsigned short* Arow = pA + (size_t)m * NG;
  const unsigned short* Bra  = pB + 0 * (size_t)NB * NG + (size_t)b * NG;
  const unsigned short* Brc  = pB + 1 * (size_t)NB * NG + (size_t)b * NG;
  const unsigned short* Bcf  = pB + 2 * (size_t)NB * NG + (size_t)b * NG;

  f32x4 accA = {0.f, 0.f, 0.f, 0.f};
  f32x4 accB = {0.f, 0.f, 0.f, 0.f};
  f32x4 accC = {0.f, 0.f, 0.f, 0.f};

  #pragma unroll
  for (int c = 0; c < KR / 32; ++c) {
    const int g = kb * KR + c * 32 + lk * 8;

    const int4 aw = *reinterpret_cast<const int4*>(Arow + g);
    int4 iaw, nfw;
    iaw.x = aw.x & 0x7FFF7FFF;  iaw.y = aw.y & 0x7FFF7FFF;
    iaw.z = aw.z & 0x7FFF7FFF;  iaw.w = aw.w & 0x7FFF7FFF;
    // sign bits -> bf16 1.0 per halfword: (t>>15)*0x3F80 (no cross-terms)
    nfw.x = (int)(((unsigned)(aw.x & 0x80008000) >> 15) * 0x3F80u);
    nfw.y = (int)(((unsigned)(aw.y & 0x80008000) >> 15) * 0x3F80u);
    nfw.z = (int)(((unsigned)(aw.z & 0x80008000) >> 15) * 0x3F80u);
    nfw.w = (int)(((unsigned)(aw.w & 0x80008000) >> 15) * 0x3F80u);
    const bf16x8 fia = __builtin_bit_cast(bf16x8, iaw);
    const bf16x8 fnf = __builtin_bit_cast(bf16x8, nfw);

    const bf16x8 fra = *reinterpret_cast<const bf16x8*>(Bra + g);
    const bf16x8 frc = *reinterpret_cast<const bf16x8*>(Brc + g);
    const bf16x8 fcf = *reinterpret_cast<const bf16x8*>(Bcf + g);

    accA = __builtin_amdgcn_mfma_f32_16x16x32_bf16(fia, fra, accA, 0, 0, 0);
    accB = __builtin_amdgcn_mfma_f32_16x16x32_bf16(fia, frc, accB, 0, 0, 0);
    accC = __builtin_amdgcn_mfma_f32_16x16x32_bf16(fnf, fcf, accC, 0, 0, 0);
  }

  // store: lane, reg i -> (m = mt*32 + mw*16 + 4*lk + i, b = bw*16 + lr)
  const int md = mt * 32 + mw * 16 + 4 * lk;
  const int bd = bw * 16 + lr;
  #pragma unroll
  for (int i = 0; i < 4; ++i) {
    part[((size_t)(kb * 3 + 0) * NM + md + i) * NB + bd] = accA[i];
    part[((size_t)(kb * 3 + 1) * NM + md + i) * NB + bd] = accB[i];
    part[((size_t)(kb * 3 + 2) * NM + md + i) * NB + bd] = accC[i];
  }
}

// grid NM: block m; tid = (kg 8 x b 32); coalesced part reads, LDS tree over kg.
__global__ __launch_bounds__(256) void k_final(const float* __restrict__ part,
                                               const float* __restrict__ sumN,
                                               float* __restrict__ out) {
  __shared__ float rA[256], rB[256], rC[256];
  const int tid = threadIdx.x;
  const int m   = blockIdx.x;
  const int b   = tid & 31;
  const int kg  = tid >> 5;             // 0..7, each covers 4 kb

  float sA = 0.f, sB = 0.f, sC = 0.f;
  #pragma unroll
  for (int t = 0; t < NKB / 8; ++t) {
    const int kb = kg * (NKB / 8) + t;
    const float* p = part + ((size_t)(kb * 3) * NM + m) * NB + b;
    sA += p[0];
    sB += p[(size_t)NM * NB];
    sC += p[2 * (size_t)NM * NB];
  }
  rA[tid] = sA; rB[tid] = sB; rC[tid] = sC;
  __syncthreads();
  if (tid < 128) { rA[tid] += rA[tid + 128]; rB[tid] += rB[tid + 128]; rC[tid] += rC[tid + 128]; }
  __syncthreads();
  if (tid < 64)  { rA[tid] += rA[tid + 64];  rB[tid] += rB[tid + 64];  rC[tid] += rC[tid + 64]; }
  __syncthreads();
  if (tid < 32) {
    const float a  = rA[tid] + rA[tid + 32];
    const float bb = rB[tid] + rB[tid + 32];
    const float c  = rC[tid] + rC[tid + 32];
    const float sN = sumN[m];
    out[(size_t)tid * NM + m] = (bb / (a + 1e-10f) - c / (sN + 1e-10f)) * (1.0f / (float)NG);
  }
}

extern "C" void kernel_launch(void* const* d_in, const int* in_sizes, int n_in,
                              void* d_out, int out_size, void* d_ws, size_t ws_size,
                              hipStream_t stream) {
  const float* R = (const float*)d_in[0];
  const int*   S = (const int*)d_in[1];
  const float* W = (const float*)d_in[2];
  float* out = (float*)d_out;

  char* ws = (char*)d_ws;
  unsigned short* pA = (unsigned short*)ws;                        // 4 MB
  unsigned short* pB = pA + (size_t)NM * NG;                       // 1.5 MB
  float* part = (float*)(ws + (size_t)NM * NG * 2 + (size_t)3 * NB * NG * 2);  // 3.2 MB
  float* sumN = part + (size_t)NKB * 3 * NM * NB;

  k_prep <<<dim3(NM + NB), dim3(256), 0, stream>>>(S, W, R, pA, pB, sumN);
  k_mm   <<<dim3(NKB, NM / 32), dim3(256), 0, stream>>>(pA, pB, part);
  k_final<<<dim3(NM), dim3(256), 0, stream>>>(part, sumN, out);
}